// Round 4
// baseline (674.443 us; speedup 1.0000x reference)
//
#include <hip/hip_runtime.h>

typedef unsigned short u16;
typedef unsigned int u32;

#define N_NODES 100000
#define N_EDGES 50000
#define C 128

static __device__ __forceinline__ float bf2f(u16 h) {
    u32 u = ((u32)h) << 16;
    float f;
    __builtin_memcpy(&f, &u, 4);
    return f;
}

static __device__ __forceinline__ u16 f2bf(float f) {
    u32 u;
    __builtin_memcpy(&u, &f, 4);
    return (u16)((u + 0x7fffu + ((u >> 16) & 1u)) >> 16);  // RNE
}

typedef short s16x8 __attribute__((ext_vector_type(8)));
typedef float f32x4 __attribute__((ext_vector_type(4)));

// ---------------- utility: zero a u32 region ----------------
__global__ void zero_k(u32* __restrict__ p, int n) {
    int i = blockIdx.x * 256 + threadIdx.x;
    if (i < n) p[i] = 0;
}

// ---------------- degree histogram ----------------
__global__ void count_k(const int* __restrict__ ni, const int* __restrict__ ei,
                        u32* __restrict__ ncnt, u32* __restrict__ ecnt, int nnz) {
    int i = blockIdx.x * 256 + threadIdx.x;
    if (i < nnz) {
        atomicAdd(&ecnt[ei[i]], 1u);
        atomicAdd(&ncnt[ni[i]], 1u);
    }
}

// ---------------- single-block exclusive scan: off[0..n], cur[i]=off[i] ------
__global__ __launch_bounds__(1024) void scan_k(const u32* __restrict__ cnt,
                                               u32* __restrict__ off,
                                               u32* __restrict__ cur, int n) {
    __shared__ u32 psum[1024];
    int t = threadIdx.x;
    int chunk = (n + 1023) / 1024;
    int lo = t * chunk;
    int hi = lo + chunk; if (hi > n) hi = n; if (lo > n) lo = n;
    u32 s = 0;
    for (int i = lo; i < hi; ++i) s += cnt[i];
    psum[t] = s;
    __syncthreads();
    for (int d = 1; d < 1024; d <<= 1) {
        u32 v = (t >= d) ? psum[t - d] : 0u;
        __syncthreads();
        psum[t] += v;
        __syncthreads();
    }
    u32 run = (t == 0) ? 0u : psum[t - 1];
    for (int i = lo; i < hi; ++i) {
        off[i] = run; cur[i] = run;
        run += cnt[i];
    }
    if (t == 1023) off[n] = run;  // tail chunks are empty -> run == total
}

// ---------------- fill CSR permutations ----------------
__global__ void fill_perm_k(const int* __restrict__ ni, const int* __restrict__ ei,
                            u32* __restrict__ ecur, u32* __restrict__ ncur,
                            u32* __restrict__ eperm, u32* __restrict__ nperm, int nnz) {
    int i = blockIdx.x * 256 + threadIdx.x;
    if (i < nnz) {
        int n = ni[i], e = ei[i];
        eperm[atomicAdd(&ecur[e], 1u)] = (u32)n;
        nperm[atomicAdd(&ncur[n], 1u)] = (u32)e;
    }
}

// ---------------- W transpose -> bf16: Wt[oc][k] = bf16(W[k][oc]) ----------
__global__ void transpose_w(const float* __restrict__ W, u16* __restrict__ Wt) {
    int idx = blockIdx.x * 256 + threadIdx.x;  // 16384 total
    int k = idx >> 7, oc = idx & 127;
    Wt[oc * 128 + k] = f2bf(W[k * 128 + oc]);
}

// ---------------- GEMM: xw[n][oc] = x[n][:] . W[:][oc], bf16 out ----------
// One wave per 16-row tile; wave computes 16(m) x 128(n) via 8 n-tiles.
// A[m=lane&15][k=quad*8+j]; B[n=lane&15][k=quad*8+j]; D col=lane&15,
// row=quad*4+reg (verified m89/m91).
__global__ __launch_bounds__(64) void gemm_xw(const float* __restrict__ x,
                                              const u16* __restrict__ Wt,
                                              u16* __restrict__ xw) {
    int lane = threadIdx.x;
    int m = lane & 15;
    int quad = lane >> 4;
    int row0 = blockIdx.x * 16;  // 100000/16 = 6250 exact

    f32x4 acc[8];
#pragma unroll
    for (int nt = 0; nt < 8; ++nt) acc[nt] = (f32x4){0.f, 0.f, 0.f, 0.f};

    for (int k0 = 0; k0 < 128; k0 += 32) {
        int kb = k0 + quad * 8;
        const float* p = x + (size_t)(row0 + m) * C + kb;
        float4 v0 = *(const float4*)p;
        float4 v1 = *(const float4*)(p + 4);
        union { uint4 u; s16x8 v; } a;
        a.u.x = (u32)f2bf(v0.x) | ((u32)f2bf(v0.y) << 16);
        a.u.y = (u32)f2bf(v0.z) | ((u32)f2bf(v0.w) << 16);
        a.u.z = (u32)f2bf(v1.x) | ((u32)f2bf(v1.y) << 16);
        a.u.w = (u32)f2bf(v1.z) | ((u32)f2bf(v1.w) << 16);
#pragma unroll
        for (int nt = 0; nt < 8; ++nt) {
            union { uint4 u; s16x8 v; } b;
            b.u = *(const uint4*)(Wt + (size_t)(nt * 16 + m) * C + kb);
            acc[nt] = __builtin_amdgcn_mfma_f32_16x16x32_bf16(a.v, b.v, acc[nt], 0, 0, 0);
        }
    }

#pragma unroll
    for (int nt = 0; nt < 8; ++nt) {
#pragma unroll
        for (int r = 0; r < 4; ++r) {
            int row = row0 + quad * 4 + r;
            xw[(size_t)row * C + nt * 16 + m] = f2bf(acc[nt][r]);
        }
    }
}

// ---------------- edge gather: ef[e] = bf16( B^-1_e * sum xw[nodes of e] ) --
// one wave per edge; lane owns channels {2*lane, 2*lane+1}
__global__ __launch_bounds__(256) void edge_gather_k(const u16* __restrict__ xw,
                                                     const u32* __restrict__ eoff,
                                                     const u32* __restrict__ eperm,
                                                     u16* __restrict__ ef) {
    int e = blockIdx.x * 4 + (threadIdx.x >> 6);
    if (e >= N_EDGES) return;
    int lane = threadIdx.x & 63;
    u32 lo = eoff[e], hi = eoff[e + 1];
    float a0 = 0.f, a1 = 0.f;
    for (u32 j = lo; j < hi; ++j) {
        u32 n = eperm[j];
        u32 u = ((const u32*)(xw + (size_t)n * C))[lane];
        a0 += bf2f((u16)(u & 0xffffu));
        a1 += bf2f((u16)(u >> 16));
    }
    float binv = (hi > lo) ? 1.f / (float)(hi - lo) : 0.f;
    u32 pack = (u32)f2bf(a0 * binv) | ((u32)f2bf(a1 * binv) << 16);
    ((u32*)(ef + (size_t)e * C))[lane] = pack;
}

// ---------------- node gather: out[v] = f32( D^-1_v * sum ef[edges] + b ) ---
// OUTPUT IS FLOAT32 (reference output dtype). float2 store per lane.
__global__ __launch_bounds__(256) void node_gather_k(const u16* __restrict__ ef,
                                                     const u32* __restrict__ noff,
                                                     const u32* __restrict__ nperm,
                                                     const float* __restrict__ bias,
                                                     float* __restrict__ out) {
    int v = blockIdx.x * 4 + (threadIdx.x >> 6);
    if (v >= N_NODES) return;
    int lane = threadIdx.x & 63;
    u32 lo = noff[v], hi = noff[v + 1];
    float a0 = 0.f, a1 = 0.f;
    for (u32 j = lo; j < hi; ++j) {
        u32 e = nperm[j];
        u32 u = ((const u32*)(ef + (size_t)e * C))[lane];
        a0 += bf2f((u16)(u & 0xffffu));
        a1 += bf2f((u16)(u >> 16));
    }
    float dinv = (hi > lo) ? 1.f / (float)(hi - lo) : 0.f;
    float b0 = bias[2 * lane], b1 = bias[2 * lane + 1];
    float2 r;
    r.x = a0 * dinv + b0;
    r.y = a1 * dinv + b1;
    ((float2*)(out + (size_t)v * C))[lane] = r;
}

extern "C" void kernel_launch(void* const* d_in, const int* in_sizes, int n_in,
                              void* d_out, int out_size, void* d_ws, size_t ws_size,
                              hipStream_t stream) {
    const float* x = (const float*)d_in[0];     // [N_NODES,128] f32 (verified R3)
    const int* node_idx = (const int*)d_in[1];  // [2, NNZ] row-major int32
    const int nnz = in_sizes[1] / 2;
    const int* edge_idx = node_idx + nnz;
    const float* W = (const float*)d_in[2];     // [128,128] f32
    const float* bias = (const float*)d_in[3];  // [128] f32
    float* out = (float*)d_out;                 // [N_NODES,128] f32 (H1)

    // workspace layout (~18.5 MB)
    u16* Wt = (u16*)d_ws;                          // 16384 u16, 16B-aligned
    u16* ef = Wt + 16384;                          // 6.4M u16 (12.8 MB)
    u32* ecnt = (u32*)(ef + (size_t)N_EDGES * C);  // 50000
    u32* ncnt = ecnt + N_EDGES;                    // 100000
    u32* eoff = ncnt + N_NODES;                    // 50001
    u32* ecur = eoff + N_EDGES + 1;                // 50000
    u32* noff = ecur + N_EDGES;                    // 100001
    u32* ncur = noff + N_NODES + 1;                // 100000
    u32* eperm = ncur + N_NODES;                   // nnz
    u32* nperm = eperm + nnz;                      // nnz

    u16* xw = (u16*)d_out;  // 25.6MB scratch in the 51.2MB f32 out buffer;
                            // consumed by edge_gather, then node_gather
                            // overwrites the whole buffer.

    zero_k<<<(N_EDGES + N_NODES + 255) / 256, 256, 0, stream>>>(ecnt, N_EDGES + N_NODES);
    count_k<<<(nnz + 255) / 256, 256, 0, stream>>>(node_idx, edge_idx, ncnt, ecnt, nnz);
    scan_k<<<1, 1024, 0, stream>>>(ecnt, eoff, ecur, N_EDGES);
    scan_k<<<1, 1024, 0, stream>>>(ncnt, noff, ncur, N_NODES);
    fill_perm_k<<<(nnz + 255) / 256, 256, 0, stream>>>(node_idx, edge_idx, ecur, ncur,
                                                       eperm, nperm, nnz);
    transpose_w<<<64, 256, 0, stream>>>(W, Wt);
    gemm_xw<<<N_NODES / 16, 64, 0, stream>>>(x, Wt, xw);
    edge_gather_k<<<(N_EDGES + 3) / 4, 256, 0, stream>>>(xw, eoff, eperm, ef);
    node_gather_k<<<(N_NODES + 3) / 4, 256, 0, stream>>>(ef, noff, nperm, bias, out);
}

// Round 5
// 356.086 us; speedup vs baseline: 1.8940x; 1.8940x over previous
//
#include <hip/hip_runtime.h>

typedef unsigned short u16;
typedef unsigned int u32;

#define N_NODES 100000
#define N_EDGES 50000
#define C 128
#define SCAN_N (N_EDGES + N_NODES)        // 150000 (ecnt || ncnt contiguous)
#define SCAN_NB ((SCAN_N + 1023) / 1024)  // 147 blocks

static __device__ __forceinline__ float bf2f(u16 h) {
    u32 u = ((u32)h) << 16;
    float f;
    __builtin_memcpy(&f, &u, 4);
    return f;
}

static __device__ __forceinline__ u16 f2bf(float f) {
    u32 u;
    __builtin_memcpy(&u, &f, 4);
    return (u16)((u + 0x7fffu + ((u >> 16) & 1u)) >> 16);  // RNE
}

typedef short s16x8 __attribute__((ext_vector_type(8)));
typedef float f32x4 __attribute__((ext_vector_type(4)));

// ---------------- utility: zero a u32 region ----------------
__global__ void zero_k(u32* __restrict__ p, int n) {
    int i = blockIdx.x * 256 + threadIdx.x;
    if (i < n) p[i] = 0;
}

// ---------------- degree histogram (combined cnt: [ecnt | ncnt]) ----------
__global__ void count_k(const int* __restrict__ ni, const int* __restrict__ ei,
                        u32* __restrict__ cnt, int nnz) {
    int i = blockIdx.x * 256 + threadIdx.x;
    if (i < nnz) {
        atomicAdd(&cnt[ei[i]], 1u);
        atomicAdd(&cnt[N_EDGES + ni[i]], 1u);
    }
}

// ---------------- hierarchical scan, pass 1: per-block sums (1024 elems) ---
__global__ __launch_bounds__(256) void bsum_k(const u32* __restrict__ cnt,
                                              u32* __restrict__ bsum, int n) {
    __shared__ u32 sm[256];
    int t = threadIdx.x;
    int base = blockIdx.x * 1024 + t * 4;
    u32 s = 0;
    if (base + 3 < n) {
        uint4 v = *(const uint4*)(cnt + base);
        s = v.x + v.y + v.z + v.w;
    } else {
#pragma unroll
        for (int j = 0; j < 4; ++j) if (base + j < n) s += cnt[base + j];
    }
    sm[t] = s;
    __syncthreads();
    for (int d = 128; d > 0; d >>= 1) {
        if (t < d) sm[t] += sm[t + d];
        __syncthreads();
    }
    if (t == 0) bsum[blockIdx.x] = sm[0];
}

// ---------------- pass 2: exclusive scan of block sums (nb <= 256) --------
__global__ __launch_bounds__(256) void scan_mid_k(const u32* __restrict__ bsum,
                                                  u32* __restrict__ bscan, int nb) {
    __shared__ u32 sm[256];
    int t = threadIdx.x;
    sm[t] = (t < nb) ? bsum[t] : 0u;
    __syncthreads();
    for (int d = 1; d < 256; d <<= 1) {
        u32 add = (t >= d) ? sm[t - d] : 0u;
        __syncthreads();
        sm[t] += add;
        __syncthreads();
    }
    bscan[t] = (t > 0) ? sm[t - 1] : 0u;  // exclusive
}

// ---------------- pass 3: apply -> off[0..n], cur[i]=off[i] ----------------
__global__ __launch_bounds__(256) void scan_apply_k(const u32* __restrict__ cnt,
                                                    const u32* __restrict__ bscan,
                                                    u32* __restrict__ off,
                                                    u32* __restrict__ cur, int n) {
    __shared__ u32 sm[256];
    int t = threadIdx.x;
    int base = blockIdx.x * 1024 + t * 4;
    u32 c0 = 0, c1 = 0, c2 = 0, c3 = 0;
    if (base + 3 < n) {
        uint4 v = *(const uint4*)(cnt + base);
        c0 = v.x; c1 = v.y; c2 = v.z; c3 = v.w;
    } else {
        if (base + 0 < n) c0 = cnt[base + 0];
        if (base + 1 < n) c1 = cnt[base + 1];
        if (base + 2 < n) c2 = cnt[base + 2];
    }
    sm[t] = c0 + c1 + c2 + c3;
    __syncthreads();
    for (int d = 1; d < 256; d <<= 1) {
        u32 add = (t >= d) ? sm[t - d] : 0u;
        __syncthreads();
        sm[t] += add;
        __syncthreads();
    }
    u32 run = bscan[blockIdx.x] + ((t > 0) ? sm[t - 1] : 0u);
    u32 c[4] = {c0, c1, c2, c3};
#pragma unroll
    for (int j = 0; j < 4; ++j) {
        int idx = base + j;
        if (idx < n) {
            off[idx] = run; cur[idx] = run;
            run += c[j];
            if (idx == n - 1) off[n] = run;
        }
    }
}

// ---------------- fill combined CSR permutation ----------------
// edge slots occupy perm[0..nnz), node slots perm[nnz..2nnz) via the
// concatenated-scan offsets.
__global__ void fill_perm_k(const int* __restrict__ ni, const int* __restrict__ ei,
                            u32* __restrict__ cur, u32* __restrict__ perm, int nnz) {
    int i = blockIdx.x * 256 + threadIdx.x;
    if (i < nnz) {
        int n = ni[i], e = ei[i];
        perm[atomicAdd(&cur[e], 1u)] = (u32)n;
        perm[atomicAdd(&cur[N_EDGES + n], 1u)] = (u32)e;
    }
}

// ---------------- W transpose -> bf16: Wt[oc][k] = bf16(W[k][oc]) ----------
__global__ void transpose_w(const float* __restrict__ W, u16* __restrict__ Wt) {
    int idx = blockIdx.x * 256 + threadIdx.x;  // 16384 total
    int k = idx >> 7, oc = idx & 127;
    Wt[oc * 128 + k] = f2bf(W[k * 128 + oc]);
}

// ---------------- GEMM: xw[n][oc] = x[n][:] . W[:][oc], bf16 out ----------
// One wave per 16-row tile; A[m=lane&15][k=quad*8+j]; D col=lane&15,
// row=quad*4+reg (verified m89/m91).
__global__ __launch_bounds__(64) void gemm_xw(const float* __restrict__ x,
                                              const u16* __restrict__ Wt,
                                              u16* __restrict__ xw) {
    int lane = threadIdx.x;
    int m = lane & 15;
    int quad = lane >> 4;
    int row0 = blockIdx.x * 16;  // 100000/16 = 6250 exact

    f32x4 acc[8];
#pragma unroll
    for (int nt = 0; nt < 8; ++nt) acc[nt] = (f32x4){0.f, 0.f, 0.f, 0.f};

    for (int k0 = 0; k0 < 128; k0 += 32) {
        int kb = k0 + quad * 8;
        const float* p = x + (size_t)(row0 + m) * C + kb;
        float4 v0 = *(const float4*)p;
        float4 v1 = *(const float4*)(p + 4);
        union { uint4 u; s16x8 v; } a;
        a.u.x = (u32)f2bf(v0.x) | ((u32)f2bf(v0.y) << 16);
        a.u.y = (u32)f2bf(v0.z) | ((u32)f2bf(v0.w) << 16);
        a.u.z = (u32)f2bf(v1.x) | ((u32)f2bf(v1.y) << 16);
        a.u.w = (u32)f2bf(v1.z) | ((u32)f2bf(v1.w) << 16);
#pragma unroll
        for (int nt = 0; nt < 8; ++nt) {
            union { uint4 u; s16x8 v; } b;
            b.u = *(const uint4*)(Wt + (size_t)(nt * 16 + m) * C + kb);
            acc[nt] = __builtin_amdgcn_mfma_f32_16x16x32_bf16(a.v, b.v, acc[nt], 0, 0, 0);
        }
    }

#pragma unroll
    for (int nt = 0; nt < 8; ++nt) {
#pragma unroll
        for (int r = 0; r < 4; ++r) {
            int row = row0 + quad * 4 + r;
            xw[(size_t)row * C + nt * 16 + m] = f2bf(acc[nt][r]);
        }
    }
}

// ---------------- edge gather: ef[e] = bf16( B^-1_e * sum xw[nodes of e] ) --
__global__ __launch_bounds__(256) void edge_gather_k(const u16* __restrict__ xw,
                                                     const u32* __restrict__ eoff,
                                                     const u32* __restrict__ perm,
                                                     u16* __restrict__ ef) {
    int e = blockIdx.x * 4 + (threadIdx.x >> 6);
    if (e >= N_EDGES) return;
    int lane = threadIdx.x & 63;
    u32 lo = eoff[e], hi = eoff[e + 1];
    float a0 = 0.f, a1 = 0.f;
    for (u32 j = lo; j < hi; ++j) {
        u32 n = perm[j];
        u32 u = ((const u32*)(xw + (size_t)n * C))[lane];
        a0 += bf2f((u16)(u & 0xffffu));
        a1 += bf2f((u16)(u >> 16));
    }
    float binv = (hi > lo) ? 1.f / (float)(hi - lo) : 0.f;
    u32 pack = (u32)f2bf(a0 * binv) | ((u32)f2bf(a1 * binv) << 16);
    ((u32*)(ef + (size_t)e * C))[lane] = pack;
}

// ---------------- node gather: out[v] = f32( D^-1_v * sum ef[edges] + b ) ---
__global__ __launch_bounds__(256) void node_gather_k(const u16* __restrict__ ef,
                                                     const u32* __restrict__ noff,
                                                     const u32* __restrict__ perm,
                                                     const float* __restrict__ bias,
                                                     float* __restrict__ out) {
    int v = blockIdx.x * 4 + (threadIdx.x >> 6);
    if (v >= N_NODES) return;
    int lane = threadIdx.x & 63;
    u32 lo = noff[v], hi = noff[v + 1];
    float a0 = 0.f, a1 = 0.f;
    for (u32 j = lo; j < hi; ++j) {
        u32 e = perm[j];
        u32 u = ((const u32*)(ef + (size_t)e * C))[lane];
        a0 += bf2f((u16)(u & 0xffffu));
        a1 += bf2f((u16)(u >> 16));
    }
    float dinv = (hi > lo) ? 1.f / (float)(hi - lo) : 0.f;
    float b0 = bias[2 * lane], b1 = bias[2 * lane + 1];
    float2 r;
    r.x = a0 * dinv + b0;
    r.y = a1 * dinv + b1;
    ((float2*)(out + (size_t)v * C))[lane] = r;
}

extern "C" void kernel_launch(void* const* d_in, const int* in_sizes, int n_in,
                              void* d_out, int out_size, void* d_ws, size_t ws_size,
                              hipStream_t stream) {
    const float* x = (const float*)d_in[0];     // [N_NODES,128] f32
    const int* node_idx = (const int*)d_in[1];  // [2, NNZ] row-major int32
    const int nnz = in_sizes[1] / 2;
    const int* edge_idx = node_idx + nnz;
    const float* W = (const float*)d_in[2];     // [128,128] f32
    const float* bias = (const float*)d_in[3];  // [128] f32
    float* out = (float*)d_out;                 // [N_NODES,128] f32

    // workspace layout (~18.6 MB)
    u16* Wt = (u16*)d_ws;                       // 16384 u16 (32 KB)
    u16* ef = Wt + 16384;                       // 6.4M u16 (12.8 MB)
    u32* cnt = (u32*)(ef + (size_t)N_EDGES * C);  // 150000 (16B-aligned)
    u32* off = cnt + SCAN_N;                    // 150001
    u32* cur = off + SCAN_N + 1;                // 150000
    u32* perm = cur + SCAN_N;                   // 2*nnz
    u32* bsum = perm + 2 * (size_t)nnz;         // 256
    u32* bscan = bsum + 256;                    // 256

    u16* xw = (u16*)d_out;  // 25.6MB scratch inside 51.2MB f32 out buffer;
                            // consumed by edge_gather, then node_gather
                            // overwrites the whole buffer.

    zero_k<<<(SCAN_N + 255) / 256, 256, 0, stream>>>(cnt, SCAN_N);
    count_k<<<(nnz + 255) / 256, 256, 0, stream>>>(node_idx, edge_idx, cnt, nnz);
    bsum_k<<<SCAN_NB, 256, 0, stream>>>(cnt, bsum, SCAN_N);
    scan_mid_k<<<1, 256, 0, stream>>>(bsum, bscan, SCAN_NB);
    scan_apply_k<<<SCAN_NB, 256, 0, stream>>>(cnt, bscan, off, cur, SCAN_N);
    fill_perm_k<<<(nnz + 255) / 256, 256, 0, stream>>>(node_idx, edge_idx, cur, perm, nnz);
    transpose_w<<<64, 256, 0, stream>>>(W, Wt);
    gemm_xw<<<N_NODES / 16, 64, 0, stream>>>(x, Wt, xw);
    edge_gather_k<<<(N_EDGES + 3) / 4, 256, 0, stream>>>(xw, off, perm, ef);
    node_gather_k<<<(N_NODES + 3) / 4, 256, 0, stream>>>(ef, off + N_EDGES, perm, bias, out);
}

// Round 6
// 277.478 us; speedup vs baseline: 2.4306x; 1.2833x over previous
//
#include <hip/hip_runtime.h>

typedef unsigned short u16;
typedef unsigned int u32;

#define N_NODES 100000
#define N_EDGES 50000
#define C 128
#define G_GEMM 1563   // 1563 blocks * 4 waves = 6252 tiles >= 6250

static __device__ __forceinline__ float bf2f(u16 h) {
    u32 u = ((u32)h) << 16;
    float f;
    __builtin_memcpy(&f, &u, 4);
    return f;
}

static __device__ __forceinline__ u16 f2bf(float f) {
    u32 u;
    __builtin_memcpy(&u, &f, 4);
    return (u16)((u + 0x7fffu + ((u >> 16) & 1u)) >> 16);  // RNE
}

typedef short s16x8 __attribute__((ext_vector_type(8)));
typedef float f32x4 __attribute__((ext_vector_type(4)));

// ---------------- W transpose -> bf16: Wt[oc][k] = bf16(W[k][oc]) ----------
__global__ void transpose_w(const float* __restrict__ W, u16* __restrict__ Wt) {
    int idx = blockIdx.x * 256 + threadIdx.x;  // 16384 total
    int k = idx >> 7, oc = idx & 127;
    Wt[oc * 128 + k] = f2bf(W[k * 128 + oc]);
}

// ---------------- fused: MFMA GEMM (blocks < G_GEMM) + list build ----------
// GEMM: xw[n][oc] = x[n][:] . W[:][oc], bf16 out. One wave per 16-row tile;
// A[m=lane&15][k=quad*8+j]; D col=lane&15, row=quad*4+reg (verified m89/m91).
// Build: per incidence i, push i onto edge list e and node list n.
// pair.x = next index (0xFFFFFFFF terminates), pair.y = payload (node / edge).
// pair writes are coalesced 8B at index i; only the head exchange scatters.
__global__ __launch_bounds__(256) void fused_gemm_build(
    const float* __restrict__ x, const u16* __restrict__ Wt,
    u16* __restrict__ xw,
    const int* __restrict__ ni, const int* __restrict__ ei,
    u32* __restrict__ headE, u32* __restrict__ headN,
    uint2* __restrict__ pairE, uint2* __restrict__ pairN, int nnz) {
    if (blockIdx.x < G_GEMM) {
        int wave = threadIdx.x >> 6;
        int tile = blockIdx.x * 4 + wave;
        if (tile >= 6250) return;
        int lane = threadIdx.x & 63;
        int m = lane & 15;
        int quad = lane >> 4;
        int row0 = tile * 16;

        f32x4 acc[8];
#pragma unroll
        for (int nt = 0; nt < 8; ++nt) acc[nt] = (f32x4){0.f, 0.f, 0.f, 0.f};

        for (int k0 = 0; k0 < 128; k0 += 32) {
            int kb = k0 + quad * 8;
            const float* p = x + (size_t)(row0 + m) * C + kb;
            float4 v0 = *(const float4*)p;
            float4 v1 = *(const float4*)(p + 4);
            union { uint4 u; s16x8 v; } a;
            a.u.x = (u32)f2bf(v0.x) | ((u32)f2bf(v0.y) << 16);
            a.u.y = (u32)f2bf(v0.z) | ((u32)f2bf(v0.w) << 16);
            a.u.z = (u32)f2bf(v1.x) | ((u32)f2bf(v1.y) << 16);
            a.u.w = (u32)f2bf(v1.z) | ((u32)f2bf(v1.w) << 16);
#pragma unroll
            for (int nt = 0; nt < 8; ++nt) {
                union { uint4 u; s16x8 v; } b;
                b.u = *(const uint4*)(Wt + (size_t)(nt * 16 + m) * C + kb);
                acc[nt] = __builtin_amdgcn_mfma_f32_16x16x32_bf16(a.v, b.v, acc[nt], 0, 0, 0);
            }
        }

#pragma unroll
        for (int nt = 0; nt < 8; ++nt) {
#pragma unroll
            for (int r = 0; r < 4; ++r) {
                int row = row0 + quad * 4 + r;
                xw[(size_t)row * C + nt * 16 + m] = f2bf(acc[nt][r]);
            }
        }
    } else {
        int i = (blockIdx.x - G_GEMM) * 256 + threadIdx.x;
        if (i < nnz) {
            int n = ni[i], e = ei[i];
            u32 oldE = atomicExch(&headE[e], (u32)i);
            pairE[i] = make_uint2(oldE, (u32)n);
            u32 oldN = atomicExch(&headN[n], (u32)i);
            pairN[i] = make_uint2(oldN, (u32)e);
        }
    }
}

// ---------------- edge gather: ef[e] = bf16( B^-1_e * sum xw[nodes of e] ) --
// one wave per edge; list chase is wave-uniform (broadcast 8B loads).
__global__ __launch_bounds__(256) void edge_gather_k(const u16* __restrict__ xw,
                                                     const u32* __restrict__ headE,
                                                     const uint2* __restrict__ pairE,
                                                     u16* __restrict__ ef) {
    int e = blockIdx.x * 4 + (threadIdx.x >> 6);
    if (e >= N_EDGES) return;
    int lane = threadIdx.x & 63;
    u32 j = headE[e];
    float a0 = 0.f, a1 = 0.f;
    int cnt = 0;
    while (j != 0xFFFFFFFFu) {
        uint2 p = pairE[j];
        u32 u = ((const u32*)(xw + (size_t)p.y * C))[lane];
        a0 += bf2f((u16)(u & 0xffffu));
        a1 += bf2f((u16)(u >> 16));
        cnt++;
        j = p.x;
    }
    float binv = cnt ? 1.f / (float)cnt : 0.f;
    u32 pack = (u32)f2bf(a0 * binv) | ((u32)f2bf(a1 * binv) << 16);
    ((u32*)(ef + (size_t)e * C))[lane] = pack;
}

// ---------------- node gather: out[v] = f32( D^-1_v * sum ef[edges] + b ) ---
__global__ __launch_bounds__(256) void node_gather_k(const u16* __restrict__ ef,
                                                     const u32* __restrict__ headN,
                                                     const uint2* __restrict__ pairN,
                                                     const float* __restrict__ bias,
                                                     float* __restrict__ out) {
    int v = blockIdx.x * 4 + (threadIdx.x >> 6);
    if (v >= N_NODES) return;
    int lane = threadIdx.x & 63;
    u32 j = headN[v];
    float a0 = 0.f, a1 = 0.f;
    int cnt = 0;
    while (j != 0xFFFFFFFFu) {
        uint2 p = pairN[j];
        u32 u = ((const u32*)(ef + (size_t)p.y * C))[lane];
        a0 += bf2f((u16)(u & 0xffffu));
        a1 += bf2f((u16)(u >> 16));
        cnt++;
        j = p.x;
    }
    float dinv = cnt ? 1.f / (float)cnt : 0.f;
    float b0 = bias[2 * lane], b1 = bias[2 * lane + 1];
    float2 r;
    r.x = a0 * dinv + b0;
    r.y = a1 * dinv + b1;
    ((float2*)(out + (size_t)v * C))[lane] = r;
}

extern "C" void kernel_launch(void* const* d_in, const int* in_sizes, int n_in,
                              void* d_out, int out_size, void* d_ws, size_t ws_size,
                              hipStream_t stream) {
    const float* x = (const float*)d_in[0];     // [N_NODES,128] f32
    const int* node_idx = (const int*)d_in[1];  // [2, NNZ] row-major int32
    const int nnz = in_sizes[1] / 2;
    const int* edge_idx = node_idx + nnz;
    const float* W = (const float*)d_in[2];     // [128,128] f32
    const float* bias = (const float*)d_in[3];  // [128] f32
    float* out = (float*)d_out;                 // [N_NODES,128] f32

    // workspace layout (~21.4 MB)
    u16* Wt = (u16*)d_ws;                          // 16384 u16 (32 KB)
    u16* ef = Wt + 16384;                          // 6.4M u16 (12.8 MB)
    u32* headE = (u32*)(ef + (size_t)N_EDGES * C); // 50000
    u32* headN = headE + N_EDGES;                  // 100000
    uint2* pairE = (uint2*)(headN + N_NODES);      // nnz * 8B (8B-aligned)
    uint2* pairN = pairE + nnz;                    // nnz * 8B

    u16* xw = (u16*)d_out;  // 25.6MB scratch inside 51.2MB f32 out buffer;
                            // consumed by edge_gather, then node_gather
                            // overwrites the whole buffer.

    // heads = 0xFFFFFFFF (list terminator)
    hipMemsetAsync(headE, 0xFF, (size_t)(N_EDGES + N_NODES) * 4, stream);
    transpose_w<<<64, 256, 0, stream>>>(W, Wt);
    fused_gemm_build<<<G_GEMM + (nnz + 255) / 256, 256, 0, stream>>>(
        x, Wt, xw, node_idx, edge_idx, headE, headN, pairE, pairN, nnz);
    edge_gather_k<<<(N_EDGES + 3) / 4, 256, 0, stream>>>(xw, headE, pairE, ef);
    node_gather_k<<<(N_NODES + 3) / 4, 256, 0, stream>>>(ef, headN, pairN, bias, out);
}

// Round 7
// 256.037 us; speedup vs baseline: 2.6342x; 1.0837x over previous
//
#include <hip/hip_runtime.h>

typedef unsigned short u16;
typedef unsigned int u32;

#define N_NODES 100000
#define N_EDGES 50000
#define C 128
#define G_GEMM 1563   // 1563 blocks * 4 waves = 6252 tiles >= 6250
#define DONE 0xFFFFFFFFu

static __device__ __forceinline__ float bf2f(u16 h) {
    u32 u = ((u32)h) << 16;
    float f;
    __builtin_memcpy(&f, &u, 4);
    return f;
}

static __device__ __forceinline__ u16 f2bf(float f) {
    u32 u;
    __builtin_memcpy(&u, &f, 4);
    return (u16)((u + 0x7fffu + ((u >> 16) & 1u)) >> 16);  // RNE
}

typedef short s16x8 __attribute__((ext_vector_type(8)));
typedef float f32x4 __attribute__((ext_vector_type(4)));

// ---------------- W transpose -> bf16: Wt[oc][k] = bf16(W[k][oc]) ----------
__global__ void transpose_w(const float* __restrict__ W, u16* __restrict__ Wt) {
    int idx = blockIdx.x * 256 + threadIdx.x;  // 16384 total
    int k = idx >> 7, oc = idx & 127;
    Wt[oc * 128 + k] = f2bf(W[k * 128 + oc]);
}

// ---------------- fused: MFMA GEMM (blocks < G_GEMM) + list build ----------
// GEMM: xw[n][oc] = x[n][:] . W[:][oc], bf16 out. One wave per 16-row tile;
// A[m=lane&15][k=quad*8+j]; D col=lane&15, row=quad*4+reg (verified m89/m91).
// Build: per incidence i, push i onto edge list e and node list n.
// pair.x = next index (DONE terminates), pair.y = payload (node / edge).
__global__ __launch_bounds__(256) void fused_gemm_build(
    const float* __restrict__ x, const u16* __restrict__ Wt,
    u16* __restrict__ xw,
    const int* __restrict__ ni, const int* __restrict__ ei,
    u32* __restrict__ headE, u32* __restrict__ headN,
    uint2* __restrict__ pairE, uint2* __restrict__ pairN, int nnz) {
    if (blockIdx.x < G_GEMM) {
        int wave = threadIdx.x >> 6;
        int tile = blockIdx.x * 4 + wave;
        if (tile >= 6250) return;
        int lane = threadIdx.x & 63;
        int m = lane & 15;
        int quad = lane >> 4;
        int row0 = tile * 16;

        f32x4 acc[8];
#pragma unroll
        for (int nt = 0; nt < 8; ++nt) acc[nt] = (f32x4){0.f, 0.f, 0.f, 0.f};

        for (int k0 = 0; k0 < 128; k0 += 32) {
            int kb = k0 + quad * 8;
            const float* p = x + (size_t)(row0 + m) * C + kb;
            float4 v0 = *(const float4*)p;
            float4 v1 = *(const float4*)(p + 4);
            union { uint4 u; s16x8 v; } a;
            a.u.x = (u32)f2bf(v0.x) | ((u32)f2bf(v0.y) << 16);
            a.u.y = (u32)f2bf(v0.z) | ((u32)f2bf(v0.w) << 16);
            a.u.z = (u32)f2bf(v1.x) | ((u32)f2bf(v1.y) << 16);
            a.u.w = (u32)f2bf(v1.z) | ((u32)f2bf(v1.w) << 16);
#pragma unroll
            for (int nt = 0; nt < 8; ++nt) {
                union { uint4 u; s16x8 v; } b;
                b.u = *(const uint4*)(Wt + (size_t)(nt * 16 + m) * C + kb);
                acc[nt] = __builtin_amdgcn_mfma_f32_16x16x32_bf16(a.v, b.v, acc[nt], 0, 0, 0);
            }
        }

#pragma unroll
        for (int nt = 0; nt < 8; ++nt) {
#pragma unroll
            for (int r = 0; r < 4; ++r) {
                int row = row0 + quad * 4 + r;
                xw[(size_t)row * C + nt * 16 + m] = f2bf(acc[nt][r]);
            }
        }
    } else {
        int i = (blockIdx.x - G_GEMM) * 256 + threadIdx.x;
        if (i < nnz) {
            int n = ni[i], e = ei[i];
            u32 oldE = atomicExch(&headE[e], (u32)i);
            pairE[i] = make_uint2(oldE, (u32)n);
            u32 oldN = atomicExch(&headN[n], (u32)i);
            pairN[i] = make_uint2(oldN, (u32)e);
        }
    }
}

// ---------------- edge gather, 4 lists per wave (MLP) ----------------------
// ef[e] = bf16( B^-1_e * sum xw[nodes of e] ); lane owns channels {2l,2l+1}.
// All chase state is wave-uniform -> predication branches are wave-uniform.
__global__ __launch_bounds__(256) void edge_gather_k(const u16* __restrict__ xw,
                                                     const u32* __restrict__ headE,
                                                     const uint2* __restrict__ pairE,
                                                     u16* __restrict__ ef) {
    int wid = blockIdx.x * 4 + (threadIdx.x >> 6);
    int e0 = wid * 4;
    if (e0 >= N_EDGES) return;
    int lane = threadIdx.x & 63;

    u32 j0 = headE[e0];
    u32 j1 = (e0 + 1 < N_EDGES) ? headE[e0 + 1] : DONE;
    u32 j2 = (e0 + 2 < N_EDGES) ? headE[e0 + 2] : DONE;
    u32 j3 = (e0 + 3 < N_EDGES) ? headE[e0 + 3] : DONE;
    float a0x = 0.f, a0y = 0.f, a1x = 0.f, a1y = 0.f;
    float a2x = 0.f, a2y = 0.f, a3x = 0.f, a3y = 0.f;
    int c0 = 0, c1 = 0, c2 = 0, c3 = 0;

    while ((j0 != DONE) | (j1 != DONE) | (j2 != DONE) | (j3 != DONE)) {
        uint2 p0, p1, p2, p3;
        if (j0 != DONE) p0 = pairE[j0];
        if (j1 != DONE) p1 = pairE[j1];
        if (j2 != DONE) p2 = pairE[j2];
        if (j3 != DONE) p3 = pairE[j3];
        if (j0 != DONE) {
            u32 u = ((const u32*)(xw + (size_t)p0.y * C))[lane];
            a0x += bf2f((u16)(u & 0xffffu)); a0y += bf2f((u16)(u >> 16));
            c0++; j0 = p0.x;
        }
        if (j1 != DONE) {
            u32 u = ((const u32*)(xw + (size_t)p1.y * C))[lane];
            a1x += bf2f((u16)(u & 0xffffu)); a1y += bf2f((u16)(u >> 16));
            c1++; j1 = p1.x;
        }
        if (j2 != DONE) {
            u32 u = ((const u32*)(xw + (size_t)p2.y * C))[lane];
            a2x += bf2f((u16)(u & 0xffffu)); a2y += bf2f((u16)(u >> 16));
            c2++; j2 = p2.x;
        }
        if (j3 != DONE) {
            u32 u = ((const u32*)(xw + (size_t)p3.y * C))[lane];
            a3x += bf2f((u16)(u & 0xffffu)); a3y += bf2f((u16)(u >> 16));
            c3++; j3 = p3.x;
        }
    }

    float s0 = c0 ? 1.f / (float)c0 : 0.f;
    float s1 = c1 ? 1.f / (float)c1 : 0.f;
    float s2 = c2 ? 1.f / (float)c2 : 0.f;
    float s3 = c3 ? 1.f / (float)c3 : 0.f;
    ((u32*)(ef + (size_t)e0 * C))[lane] =
        (u32)f2bf(a0x * s0) | ((u32)f2bf(a0y * s0) << 16);
    if (e0 + 1 < N_EDGES)
        ((u32*)(ef + (size_t)(e0 + 1) * C))[lane] =
            (u32)f2bf(a1x * s1) | ((u32)f2bf(a1y * s1) << 16);
    if (e0 + 2 < N_EDGES)
        ((u32*)(ef + (size_t)(e0 + 2) * C))[lane] =
            (u32)f2bf(a2x * s2) | ((u32)f2bf(a2y * s2) << 16);
    if (e0 + 3 < N_EDGES)
        ((u32*)(ef + (size_t)(e0 + 3) * C))[lane] =
            (u32)f2bf(a3x * s3) | ((u32)f2bf(a3y * s3) << 16);
}

// ---------------- node gather, 4 lists per wave (MLP) ----------------------
// out[v] = f32( D^-1_v * sum ef[edges of v] + b )
__global__ __launch_bounds__(256) void node_gather_k(const u16* __restrict__ ef,
                                                     const u32* __restrict__ headN,
                                                     const uint2* __restrict__ pairN,
                                                     const float* __restrict__ bias,
                                                     float* __restrict__ out) {
    int wid = blockIdx.x * 4 + (threadIdx.x >> 6);
    int v0 = wid * 4;
    if (v0 >= N_NODES) return;
    int lane = threadIdx.x & 63;

    u32 j0 = headN[v0];
    u32 j1 = (v0 + 1 < N_NODES) ? headN[v0 + 1] : DONE;
    u32 j2 = (v0 + 2 < N_NODES) ? headN[v0 + 2] : DONE;
    u32 j3 = (v0 + 3 < N_NODES) ? headN[v0 + 3] : DONE;
    float a0x = 0.f, a0y = 0.f, a1x = 0.f, a1y = 0.f;
    float a2x = 0.f, a2y = 0.f, a3x = 0.f, a3y = 0.f;
    int c0 = 0, c1 = 0, c2 = 0, c3 = 0;

    while ((j0 != DONE) | (j1 != DONE) | (j2 != DONE) | (j3 != DONE)) {
        uint2 p0, p1, p2, p3;
        if (j0 != DONE) p0 = pairN[j0];
        if (j1 != DONE) p1 = pairN[j1];
        if (j2 != DONE) p2 = pairN[j2];
        if (j3 != DONE) p3 = pairN[j3];
        if (j0 != DONE) {
            u32 u = ((const u32*)(ef + (size_t)p0.y * C))[lane];
            a0x += bf2f((u16)(u & 0xffffu)); a0y += bf2f((u16)(u >> 16));
            c0++; j0 = p0.x;
        }
        if (j1 != DONE) {
            u32 u = ((const u32*)(ef + (size_t)p1.y * C))[lane];
            a1x += bf2f((u16)(u & 0xffffu)); a1y += bf2f((u16)(u >> 16));
            c1++; j1 = p1.x;
        }
        if (j2 != DONE) {
            u32 u = ((const u32*)(ef + (size_t)p2.y * C))[lane];
            a2x += bf2f((u16)(u & 0xffffu)); a2y += bf2f((u16)(u >> 16));
            c2++; j2 = p2.x;
        }
        if (j3 != DONE) {
            u32 u = ((const u32*)(ef + (size_t)p3.y * C))[lane];
            a3x += bf2f((u16)(u & 0xffffu)); a3y += bf2f((u16)(u >> 16));
            c3++; j3 = p3.x;
        }
    }

    float b0 = bias[2 * lane], b1 = bias[2 * lane + 1];
    float s0 = c0 ? 1.f / (float)c0 : 0.f;
    float s1 = c1 ? 1.f / (float)c1 : 0.f;
    float s2 = c2 ? 1.f / (float)c2 : 0.f;
    float s3 = c3 ? 1.f / (float)c3 : 0.f;
    float2 r;
    r.x = a0x * s0 + b0; r.y = a0y * s0 + b1;
    ((float2*)(out + (size_t)v0 * C))[lane] = r;
    if (v0 + 1 < N_NODES) {
        r.x = a1x * s1 + b0; r.y = a1y * s1 + b1;
        ((float2*)(out + (size_t)(v0 + 1) * C))[lane] = r;
    }
    if (v0 + 2 < N_NODES) {
        r.x = a2x * s2 + b0; r.y = a2y * s2 + b1;
        ((float2*)(out + (size_t)(v0 + 2) * C))[lane] = r;
    }
    if (v0 + 3 < N_NODES) {
        r.x = a3x * s3 + b0; r.y = a3y * s3 + b1;
        ((float2*)(out + (size_t)(v0 + 3) * C))[lane] = r;
    }
}

extern "C" void kernel_launch(void* const* d_in, const int* in_sizes, int n_in,
                              void* d_out, int out_size, void* d_ws, size_t ws_size,
                              hipStream_t stream) {
    const float* x = (const float*)d_in[0];     // [N_NODES,128] f32
    const int* node_idx = (const int*)d_in[1];  // [2, NNZ] row-major int32
    const int nnz = in_sizes[1] / 2;
    const int* edge_idx = node_idx + nnz;
    const float* W = (const float*)d_in[2];     // [128,128] f32
    const float* bias = (const float*)d_in[3];  // [128] f32
    float* out = (float*)d_out;                 // [N_NODES,128] f32

    // workspace layout (~21.4 MB)
    u16* Wt = (u16*)d_ws;                          // 16384 u16 (32 KB)
    u16* ef = Wt + 16384;                          // 6.4M u16 (12.8 MB)
    u32* headE = (u32*)(ef + (size_t)N_EDGES * C); // 50000
    u32* headN = headE + N_EDGES;                  // 100000
    uint2* pairE = (uint2*)(headN + N_NODES);      // nnz * 8B (8B-aligned)
    uint2* pairN = pairE + nnz;                    // nnz * 8B

    u16* xw = (u16*)d_out;  // 25.6MB scratch inside 51.2MB f32 out buffer;
                            // consumed by edge_gather, then node_gather
                            // overwrites the whole buffer.

    hipMemsetAsync(headE, 0xFF, (size_t)(N_EDGES + N_NODES) * 4, stream);
    transpose_w<<<64, 256, 0, stream>>>(W, Wt);
    fused_gemm_build<<<G_GEMM + (nnz + 255) / 256, 256, 0, stream>>>(
        x, Wt, xw, node_idx, edge_idx, headE, headN, pairE, pairN, nnz);
    // 4 lists per wave, 4 waves per block
    edge_gather_k<<<(N_EDGES + 15) / 16, 256, 0, stream>>>(xw, headE, pairE, ef);
    node_gather_k<<<(N_NODES + 15) / 16, 256, 0, stream>>>(ef, headN, pairN, bias, out);
}